// Round 1
// baseline (134.625 us; speedup 1.0000x reference)
//
#include <hip/hip_runtime.h>
#include <math.h>

#define NB  32
#define NKC 128
#define DH  64
#define NEX 1024
#define G3  192

// ws layout (floats)
#define XOFF    0          // 32*64   = 2048
#define KCIOFF  2048       // 32*128  = 4096
#define DPOFF   6144       // 32*64*128 = 262144   [b][d][i]  (TRANSPOSED)
#define FLAGOFF 268288     // 64 ints: xflag[32], done[32]
#define FLAGBYTE (FLAGOFF * 4)

// LDS union layout (floats) — phase B (tgru) and phase C (update) overlap;
// S_NEWH is written in phase B epilogue and read in phase C (must not alias).
#define S_WHH   0       // B: whh68 6912 ; B: fwA 4352 ; C: dpT 8448 / ul68 / wih36
#define S_WIH   6912    // B: wih68 6912 ; B: dptT 1088 ; C: whh36 (6912..13824)
#define S_HT    13824   // 1024
#define S_DLT   14848   // 1024
#define S_XS    15872   // 64
#define S_KRED  15936   // 512
#define S_GIS   16448   // 192
#define S_BHH3  16640   // 192
#define S_KCIL  16832   // 16
// phase C only
#define S_DPT   0       // 64*132 = 8448
#define S_FWB   8448    // 4352 ; later wjT 16*132 = 2112
#define S_WKT   12800   // 1088
#define S_PJS   13888   // 1024
#define S_OUTJ  14912   // 1024
#define S_EPS   15936   // 1024
#define S_NEWH  17024   // 1024  (live from phase B epilogue to end)
#define S_KCIF  18048   // 128
#define S_KCJ   18176   // 16
#define S_BIH   18192   // 192
#define S_BHH   18384   // 192
#define SM_SIZE 18576   // 74.3 KB -> 2 blocks/CU capacity, grid=256 co-resident

__device__ __forceinline__ float sigf(float x) { return 1.0f / (1.0f + expf(-x)); }
__device__ __forceinline__ float dot4(float4 a, float4 b) {
    return fmaf(a.x, b.x, fmaf(a.y, b.y, fmaf(a.z, b.z, a.w * b.w)));
}

__global__ __launch_bounds__(512) void kF(
    const float* __restrict__ h, const float* __restrict__ ex,
    const float* __restrict__ su, const float* __restrict__ ex_graph,
    const float* __restrict__ kc_gamma,
    const float* __restrict__ W_ex, const float* __restrict__ W_kc,
    const float* __restrict__ tgru_wih, const float* __restrict__ tgru_whh,
    const float* __restrict__ tgru_bih, const float* __restrict__ tgru_bhh,
    const float* __restrict__ fpart_w, const float* __restrict__ fpart_b,
    const float* __restrict__ ulin_w, const float* __restrict__ ulin_b,
    const float* __restrict__ ugru_wih, const float* __restrict__ ugru_whh,
    const float* __restrict__ ugru_bih, const float* __restrict__ ugru_bhh,
    float* __restrict__ ws, float* __restrict__ out)
{
    int t = threadIdx.x, wave = t >> 6, lane = t & 63;
    int b  = blockIdx.x >> 3;
    int ck = blockIdx.x & 7;
    int i0 = ck * 16;

    __shared__ __align__(16) float sm[SM_SIZE];
    int* fx = (int*)(ws + FLAGOFF);   // x ready counters, per b
    int* fd = fx + 32;                // dpart/kci ready counters, per b

    // ---------------- Phase A: x[b][ck*8 + wave]  (k0 fold; 1 d per wave)
    {
        float sub = su[b];
        const float* exb = ex + (size_t)b * NEX;
        float er[16];
        #pragma unroll
        for (int i = 0; i < 16; ++i) er[i] = exb[lane + i * 64];
        int d = ck * 8 + wave;
        const float* wr = W_ex + (size_t)d * (2 * NEX);
        float a1 = 0.f, a2 = 0.f;
        #pragma unroll
        for (int i = 0; i < 16; ++i) {
            int k = lane + i * 64;
            a1 = fmaf(er[i], wr[k], a1);
            a2 = fmaf(er[i], wr[NEX + k], a2);
        }
        float v = sub * a1 + (1.0f - sub) * a2;
        #pragma unroll
        for (int off = 32; off; off >>= 1) v += __shfl_down(v, off, 64);
        if (lane == 0) ws[XOFF + b * DH + d] = v;
    }
    __syncthreads();
    if (t == 0)
        __hip_atomic_fetch_add(fx + b, 1, __ATOMIC_RELEASE, __HIP_MEMORY_SCOPE_AGENT);

    // ---------------- Phase B: kci + tgru + new_h + dpart (k1 body)
    {
        int i = t & 15, ks = t >> 4, kb = ks * 32;
        const float* exb = ex + (size_t)b * NEX;
        const float* eg = ex_graph + i0 + i;
        float a = 0.f;
        #pragma unroll 4
        for (int k = 0; k < 32; ++k)
            a = fmaf(exb[kb + k], eg[(size_t)(kb + k) * NKC], a);
        sm[S_KRED + t] = a;
    }
    {
        const float* hb = h + (size_t)(b * NKC + i0) * DH;
        for (int idx = t; idx < 16 * DH; idx += 512) sm[S_HT + idx] = hb[idx];
    }
    if (t < G3) sm[S_BHH3 + t] = tgru_bhh[t];
    __syncthreads();
    if (t < 16) {
        float s = 0.f;
        #pragma unroll
        for (int r = 0; r < 32; ++r) s += sm[S_KRED + r * 16 + t];
        sm[S_KCIL + t] = s;
        ws[KCIOFF + b * NKC + i0 + t] = s;
    }
    if (t == 0) {
        while (__hip_atomic_load(fx + b, __ATOMIC_ACQUIRE, __HIP_MEMORY_SCOPE_AGENT) < 8)
            __builtin_amdgcn_s_sleep(1);
    }
    __syncthreads();
    if (t < DH) sm[S_XS + t] = ws[XOFF + b * DH + t];

    float giA = (t < G3) ? tgru_bih[t] : 0.f;
    float ar[2], az[2], an[2];
    #pragma unroll
    for (int m = 0; m < 2; ++m) {
        ar[m] = sm[S_BHH3 + lane];
        az[m] = sm[S_BHH3 + 64 + lane];
        an[m] = sm[S_BHH3 + 128 + lane];
    }
    for (int ch = 0; ch < 2; ++ch) {
        __syncthreads();
        for (int idx = t; idx < G3 * 8; idx += 512) {
            int row = idx >> 3, q = idx & 7;
            *(float4*)&sm[S_WHH + row * 36 + 4 * q] =
                *(const float4*)&tgru_whh[row * DH + ch * 32 + 4 * q];
            *(float4*)&sm[S_WIH + row * 36 + 4 * q] =
                *(const float4*)&tgru_wih[row * DH + ch * 32 + 4 * q];
        }
        __syncthreads();
        if (t < G3) {
            #pragma unroll
            for (int q = 0; q < 8; ++q) {
                float4 wv = *(float4*)&sm[S_WIH + t * 36 + 4 * q];
                float4 xv = *(float4*)&sm[S_XS + ch * 32 + 4 * q];
                giA += dot4(wv, xv);
            }
        }
        #pragma unroll
        for (int q = 0; q < 8; ++q) {
            float4 wr = *(float4*)&sm[S_WHH + lane * 36 + 4 * q];
            float4 wz = *(float4*)&sm[S_WHH + (64 + lane) * 36 + 4 * q];
            float4 wn = *(float4*)&sm[S_WHH + (128 + lane) * 36 + 4 * q];
            int kb2 = ch * 32 + 4 * q;
            #pragma unroll
            for (int m = 0; m < 2; ++m) {
                float4 hk = *(float4*)&sm[S_HT + (wave * 2 + m) * DH + kb2];  // bcast
                ar[m] += dot4(wr, hk);
                az[m] += dot4(wz, hk);
                an[m] += dot4(wn, hk);
            }
        }
    }
    if (t < G3) sm[S_GIS + t] = giA;
    __syncthreads();
    #pragma unroll
    for (int m = 0; m < 2; ++m) {
        int il = wave * 2 + m;
        float hval = sm[S_HT + il * DH + lane];
        float r = sigf(sm[S_GIS + lane] + ar[m]);
        float z = sigf(sm[S_GIS + 64 + lane] + az[m]);
        float n = tanhf(sm[S_GIS + 128 + lane] + r * an[m]);
        float th = (1.0f - z) * n + z * hval;
        float kv = sm[S_KCIL + il];
        float nh = (1.0f - kv) * hval + kv * th;
        sm[S_NEWH + il * DH + lane] = nh;          // stays in LDS for phase C
        sm[S_DLT + il * DH + lane] = kv * (th - hval);
    }
    __syncthreads();
    // dpart = delta_h @ fpart_w[:, :64].T
    for (int idx = t; idx < 64 * 16; idx += 512) {
        int d = idx >> 4, q = idx & 15;
        *(float4*)&sm[S_WHH + d * 68 + 4 * q] = *(const float4*)&fpart_w[d * 128 + 4 * q];
    }
    __syncthreads();
    float acc[2] = {0.f, 0.f};
    #pragma unroll
    for (int q = 0; q < 16; ++q) {
        float4 w = *(float4*)&sm[S_WHH + lane * 68 + 4 * q];
        #pragma unroll
        for (int m = 0; m < 2; ++m) {
            float4 dv = *(float4*)&sm[S_DLT + (wave * 2 + m) * DH + 4 * q];  // bcast
            acc[m] += dot4(w, dv);
        }
    }
    __syncthreads();
    #pragma unroll
    for (int m = 0; m < 2; ++m) sm[S_WIH + lane * 17 + wave * 2 + m] = acc[m];
    __syncthreads();
    for (int idx = t; idx < 1024; idx += 512) {
        int d = idx >> 4, il = idx & 15;
        ws[DPOFF + (size_t)b * 8192 + d * NKC + i0 + il] = sm[S_WIH + d * 17 + il];
    }
    __syncthreads();
    if (t == 0)
        __hip_atomic_fetch_add(fd + b, 1, __ATOMIC_RELEASE, __HIP_MEMORY_SCOPE_AGENT);

    // ---------------- Phase C: epart + partj + outj + ugru + h_out (kB body)
    // stage block-independent weights WHILE other chunks of b finish
    for (int idx = t; idx < 64 * 16; idx += 512) {
        int d = idx >> 4, q = idx & 15;
        *(float4*)&sm[S_FWB + d * 68 + 4 * q] =
            *(const float4*)&fpart_w[d * 128 + 64 + 4 * q];
    }
    for (int idx = t; idx < 1024; idx += 512) {
        int cc = idx >> 4, jl = idx & 15;
        sm[S_WKT + jl * 68 + cc] = W_kc[(size_t)cc * NKC + i0 + jl];
    }
    if (t < G3) { sm[S_BIH + t] = ugru_bih[t]; sm[S_BHH + t] = ugru_bhh[t]; }
    if (t == 0) {
        while (__hip_atomic_load(fd + b, __ATOMIC_ACQUIRE, __HIP_MEMORY_SCOPE_AGENT) < 8)
            __builtin_amdgcn_s_sleep(1);
    }
    __syncthreads();
    // cross-chunk data: dpT (all d x all i of b) + kciF (all i)
    {
        const float* dp = ws + DPOFF + (size_t)b * 8192;
        #pragma unroll
        for (int r = 0; r < 4; ++r) {
            int idx4 = t + r * 512;
            int d = idx4 >> 5, qi = idx4 & 31;
            *(float4*)&sm[S_DPT + d * 132 + 4 * qi] = *(const float4*)&dp[d * NKC + 4 * qi];
        }
    }
    if (t < NKC) sm[S_KCIF + t] = ws[KCIOFF + b * NKC + t];
    __syncthreads();
    // epart[jl,d] = fpart_b[d] + sum_c wk[c,jl]*fpart_w[d,64+c]
    #pragma unroll
    for (int r = 0; r < 2; ++r) {
        int idx = t + r * 512;
        int jl = idx >> 6, d = idx & 63;
        float a = fpart_b[d];
        #pragma unroll
        for (int q = 0; q < 16; ++q) {
            float4 fv = *(float4*)&sm[S_FWB + d * 68 + 4 * q];
            float4 wv = *(float4*)&sm[S_WKT + jl * 68 + 4 * q];
            a += dot4(fv, wv);
        }
        sm[S_EPS + jl * DH + d] = a;
    }
    __syncthreads();   // fwB/wkT dead
    // wjT [jl][i], stride 132 (reuses S_FWB region)
    for (int idx = t; idx < 2048; idx += 512) {
        int i = idx >> 4, jl = idx & 15;
        sm[S_FWB + jl * 132 + i] = sm[S_KCIF + i] * sigf(kc_gamma[i * NKC + i0 + jl]);
    }
    __syncthreads();
    if (t < 16) {
        float s = 0.f;
        #pragma unroll
        for (int qi = 0; qi < 32; ++qi) {
            float4 v = *(float4*)&sm[S_FWB + t * 132 + 4 * qi];
            s += v.x + v.y + v.z + v.w;
        }
        sm[S_KCJ + t] = s;
    }
    // partj
    float ep[2], pa[2];
    #pragma unroll
    for (int m = 0; m < 2; ++m) {
        ep[m] = sm[S_EPS + (wave * 2 + m) * DH + lane];
        pa[m] = 0.f;
    }
    for (int qi = 0; qi < 32; ++qi) {
        float4 dv = *(float4*)&sm[S_DPT + lane * 132 + 4 * qi];
        #pragma unroll
        for (int m = 0; m < 2; ++m) {
            float4 wv = *(float4*)&sm[S_FWB + (wave * 2 + m) * 132 + 4 * qi];  // bcast
            pa[m] = fmaf(fmaxf(dv.x + ep[m], 0.f), wv.x, pa[m]);
            pa[m] = fmaf(fmaxf(dv.y + ep[m], 0.f), wv.y, pa[m]);
            pa[m] = fmaf(fmaxf(dv.z + ep[m], 0.f), wv.z, pa[m]);
            pa[m] = fmaf(fmaxf(dv.w + ep[m], 0.f), wv.w, pa[m]);
        }
    }
    #pragma unroll
    for (int m = 0; m < 2; ++m) sm[S_PJS + (wave * 2 + m) * DH + lane] = pa[m];
    __syncthreads();
    // outj = relu(pj @ ulin_w.T + b) ; ul68 reuses sm[0..] (dpT dead)
    for (int idx = t; idx < 64 * 16; idx += 512) {
        int d = idx >> 4, q = idx & 15;
        *(float4*)&sm[d * 68 + 4 * q] = *(const float4*)&ulin_w[d * DH + 4 * q];
    }
    float ulb = ulin_b[lane];
    __syncthreads();
    float oa[2] = {ulb, ulb};
    #pragma unroll
    for (int q = 0; q < 16; ++q) {
        float4 uv = *(float4*)&sm[lane * 68 + 4 * q];
        #pragma unroll
        for (int m = 0; m < 2; ++m) {
            float4 pv = *(float4*)&sm[S_PJS + (wave * 2 + m) * DH + 4 * q];  // bcast
            oa[m] += dot4(uv, pv);
        }
    }
    #pragma unroll
    for (int m = 0; m < 2; ++m)
        sm[S_OUTJ + (wave * 2 + m) * DH + lane] = fmaxf(oa[m], 0.f);
    // ugru: k-chunked row-major stride-36 weights (wih36 at 0, whh36 at 6912)
    float gir[2], giz[2], gin[2], ghr[2], ghz[2], ghn[2];
    #pragma unroll
    for (int m = 0; m < 2; ++m)
        gir[m] = giz[m] = gin[m] = ghr[m] = ghz[m] = ghn[m] = 0.f;
    for (int ch = 0; ch < 2; ++ch) {
        __syncthreads();   // covers ul68/outjS deps
        for (int idx = t; idx < G3 * 8; idx += 512) {
            int row = idx >> 3, q = idx & 7;
            *(float4*)&sm[row * 36 + 4 * q] =
                *(const float4*)&ugru_wih[row * DH + ch * 32 + 4 * q];
            *(float4*)&sm[6912 + row * 36 + 4 * q] =
                *(const float4*)&ugru_whh[row * DH + ch * 32 + 4 * q];
        }
        __syncthreads();
        #pragma unroll
        for (int q = 0; q < 8; ++q) {
            float4 wir = *(float4*)&sm[lane * 36 + 4 * q];
            float4 wiz = *(float4*)&sm[(64 + lane) * 36 + 4 * q];
            float4 win = *(float4*)&sm[(128 + lane) * 36 + 4 * q];
            float4 wwr = *(float4*)&sm[6912 + lane * 36 + 4 * q];
            float4 wwz = *(float4*)&sm[6912 + (64 + lane) * 36 + 4 * q];
            float4 wwn = *(float4*)&sm[6912 + (128 + lane) * 36 + 4 * q];
            int kb2 = ch * 32 + 4 * q;
            #pragma unroll
            for (int m = 0; m < 2; ++m) {
                int jl = wave * 2 + m;
                float4 ov = *(float4*)&sm[S_OUTJ + jl * DH + kb2];  // bcast
                float4 nv = *(float4*)&sm[S_NEWH + jl * DH + kb2];  // bcast
                gir[m] += dot4(wir, ov);
                giz[m] += dot4(wiz, ov);
                gin[m] += dot4(win, ov);
                ghr[m] += dot4(wwr, nv);
                ghz[m] += dot4(wwz, nv);
                ghn[m] += dot4(wwn, nv);
            }
        }
    }
    #pragma unroll
    for (int m = 0; m < 2; ++m) {
        int jl = wave * 2 + m;
        float r = sigf(gir[m] + sm[S_BIH + lane] + ghr[m] + sm[S_BHH + lane]);
        float z = sigf(giz[m] + sm[S_BIH + 64 + lane] + ghz[m] + sm[S_BHH + 64 + lane]);
        float n = tanhf(gin[m] + sm[S_BIH + 128 + lane] +
                        r * (ghn[m] + sm[S_BHH + 128 + lane]));
        float nh = sm[S_NEWH + jl * DH + lane];
        float uh = (1.0f - z) * n + z * nh;
        float kj = sm[S_KCJ + jl];
        out[(size_t)(b * NKC + i0 + jl) * DH + lane] = (1.0f - kj) * nh + kj * uh;
    }
}

extern "C" void kernel_launch(void* const* d_in, const int* in_sizes, int n_in,
                              void* d_out, int out_size, void* d_ws, size_t ws_size,
                              hipStream_t stream) {
    const float* h        = (const float*)d_in[0];
    const float* ex       = (const float*)d_in[1];
    const float* su       = (const float*)d_in[2];
    const float* ex_graph = (const float*)d_in[3];
    const float* kc_gamma = (const float*)d_in[4];
    const float* W_ex     = (const float*)d_in[5];
    const float* W_kc     = (const float*)d_in[6];
    const float* tgru_wih = (const float*)d_in[7];
    const float* tgru_whh = (const float*)d_in[8];
    const float* tgru_bih = (const float*)d_in[9];
    const float* tgru_bhh = (const float*)d_in[10];
    const float* fpart_w  = (const float*)d_in[11];
    const float* fpart_b  = (const float*)d_in[12];
    const float* ulin_w   = (const float*)d_in[13];
    const float* ulin_b   = (const float*)d_in[14];
    const float* ugru_wih = (const float*)d_in[15];
    const float* ugru_whh = (const float*)d_in[16];
    const float* ugru_bih = (const float*)d_in[17];
    const float* ugru_bhh = (const float*)d_in[18];
    float* ws  = (float*)d_ws;
    float* out = (float*)d_out;

    // zero the per-b flag counters (workspace is poisoned between runs)
    hipMemsetAsync((char*)d_ws + FLAGBYTE, 0, 64 * sizeof(int), stream);
    hipLaunchKernelGGL(kF, dim3(256), dim3(512), 0, stream,
                       h, ex, su, ex_graph, kc_gamma, W_ex, W_kc,
                       tgru_wih, tgru_whh, tgru_bih, tgru_bhh,
                       fpart_w, fpart_b, ulin_w, ulin_b,
                       ugru_wih, ugru_whh, ugru_bih, ugru_bhh,
                       ws, out);
}